// Round 17
// baseline (567.013 us; speedup 1.0000x reference)
//
#include <hip/hip_runtime.h>
#include <hip/hip_bf16.h>

#define DEVINL __device__ __forceinline__

typedef __attribute__((ext_vector_type(8))) short bf16x8;
typedef __attribute__((ext_vector_type(4))) float f32x4;

// f32 -> bf16 round-nearest-even (bit manipulation; values are finite)
DEVINL ushort f2bf(float f) {
  unsigned u = __float_as_uint(f);
  u += 0x7fffu + ((u >> 16) & 1u);
  return (ushort)(u >> 16);
}

DEVINL void gl_lds16(const void* g, void* lds) {
  __builtin_amdgcn_global_load_lds(
      (const __attribute__((address_space(1))) void*)g,
      (__attribute__((address_space(3))) void*)lds, 16, 0, 0);
}

DEVINL f32x4 mfma16(bf16x8 a, bf16x8 b, f32x4 c) {
  return __builtin_amdgcn_mfma_f32_16x16x32_bf16(a, b, c, 0, 0, 0);
}

// ======================= fused cast f32 -> bf16 (exact shapes) =======================
__global__ __launch_bounds__(256) void cast_all_kernel(const float4* __restrict__ x,
                                                       const float4* __restrict__ wq,
                                                       const float4* __restrict__ wk,
                                                       const float4* __restrict__ wv,
                                                       const float4* __restrict__ wo,
                                                       ushort4* __restrict__ xb,
                                                       ushort4* __restrict__ wqb,
                                                       ushort4* __restrict__ wkb,
                                                       ushort4* __restrict__ wvb,
                                                       ushort4* __restrict__ wob) {
  const int blk = (int)blockIdx.x;
  const float4* src;
  ushort4* dst;
  int base;
  if (blk < 2048)      { src = x;  dst = xb;  base = blk; }
  else if (blk < 3072) { src = wq; dst = wqb; base = blk - 2048; }
  else if (blk < 4096) { src = wk; dst = wkb; base = blk - 3072; }
  else if (blk < 5120) { src = wv; dst = wvb; base = blk - 4096; }
  else                 { src = wo; dst = wob; base = blk - 5120; }
  const int idx0 = base * 1024 + (int)threadIdx.x;
#pragma unroll
  for (int i = 0; i < 4; ++i) {
    const int idx = idx0 + i * 256;
    float4 v = src[idx];
    dst[idx] = make_ushort4(f2bf(v.x), f2bf(v.y), f2bf(v.z), f2bf(v.w));
  }
}

// ============ QKV GEMM: 256^2 tile, 8 waves, 4-phase interleaved schedule ============
// T3+T4+T5: per K-tile, 4 phases of {issue 2 staging loads (t+1) | ds_read A-quadrant |
// 16 MFMA under setprio}, barriers per phase (wave role-split), counted vmcnt(2) only
// at phase 0 (oldest-first retirement => all 8 of tile t's loads landed). B-fragments
// read once per tile (phase 0) and held in registers. Frag-order LDS (conflict-free).
// col segment 0 -> Q, 1 -> K, 2 -> V^T per batch.
__global__ __launch_bounds__(512, 2) void gemm_qkv(const ushort* __restrict__ A,
                                                   const ushort* __restrict__ Bm,
                                                   ushort* __restrict__ Qo,
                                                   ushort* __restrict__ Ko,
                                                   ushort* __restrict__ Vo,
                                                   int M, int N, int K) {
  __shared__ __align__(16) ushort Al[2][16384];  // [f:16][ks:2][lane:64][8]
  __shared__ __align__(16) ushort Bl[2][16384];
  const int tid = (int)threadIdx.x;
  const int l = tid & 63, w = tid >> 6;
  const int wr = w >> 2, wc = w & 3;      // wave grid 2M x 4N; per-wave C = 128x64
  const int lr = l & 15, lg = l >> 4;
  const int wh = w >> 1, wk = w & 1;      // staging role: f-offset, ks

  // bijective XCD-chunked swizzle (384 blocks, %8==0)
  const int nwg = (int)(gridDim.x * gridDim.y);
  const int flat = (int)(blockIdx.y * gridDim.x + blockIdx.x);
  const int swz = (flat & 7) * (nwg >> 3) + (flat >> 3);
  const int bx = swz % (int)gridDim.x, by = swz / (int)gridDim.x;
  const int rowT = by * 256, colT = bx * 256;

  f32x4 acc[8][4] = {};

  // staging instr a (a=0..3): stages f in {4a..4a+3} x both ks for one matrix.
  // thread role: f = 4a + (w>>1), ks = w&1; lane covers 16 rows x 4 k-octets.
  auto stageA = [&](int kt, int buf, int a) {
    const int f = a * 4 + wh;
    gl_lds16(A + (size_t)(rowT + f * 16 + lr) * K + (size_t)(kt + wk * 32 + lg * 8),
             &Al[buf][(size_t)(((f * 2 + wk) * 64) * 8)]);
  };
  auto stageB = [&](int kt, int buf, int a) {
    const int f = a * 4 + wh;
    gl_lds16(Bm + (size_t)(colT + f * 16 + lr) * K + (size_t)(kt + wk * 32 + lg * 8),
             &Bl[buf][(size_t)(((f * 2 + wk) * 64) * 8)]);
  };

  // prologue: fully stage tile 0
#pragma unroll
  for (int a = 0; a < 4; ++a) { stageA(0, 0, a); stageB(0, 0, a); }

  int cur = 0;
  for (int kt = 0; kt < K; kt += 64) {
    const bool notlast = (kt + 64 < K);
    bf16x8 bfv[4][2];  // B fragments cached for the whole tile

    // ---------- phase 0 ----------
    if (notlast) {
      stageA(kt + 64, cur ^ 1, 0);
      stageB(kt + 64, cur ^ 1, 0);
      asm volatile("s_waitcnt vmcnt(2)" ::: "memory");  // all of tile t landed
    } else {
      asm volatile("s_waitcnt vmcnt(0)" ::: "memory");
    }
    __builtin_amdgcn_sched_barrier(0);
    __builtin_amdgcn_s_barrier();
    __builtin_amdgcn_sched_barrier(0);
#pragma unroll
    for (int j = 0; j < 4; ++j)
#pragma unroll
      for (int ks = 0; ks < 2; ++ks)
        bfv[j][ks] = *(const bf16x8*)(&Bl[cur][((((wc * 4 + j) * 2 + ks) * 64 + l) * 8)]);
    {
      bf16x8 af[2][2];
#pragma unroll
      for (int i = 0; i < 2; ++i)
#pragma unroll
        for (int ks = 0; ks < 2; ++ks)
          af[i][ks] = *(const bf16x8*)(&Al[cur][(((((wr * 8 + i) * 2) + ks) * 64 + l) * 8)]);
      __builtin_amdgcn_s_setprio(1);
#pragma unroll
      for (int ks = 0; ks < 2; ++ks)
#pragma unroll
        for (int i = 0; i < 2; ++i)
#pragma unroll
          for (int j = 0; j < 4; ++j)
            acc[i][j] = mfma16(af[i][ks], bfv[j][ks], acc[i][j]);
      __builtin_amdgcn_s_setprio(0);
    }

    // ---------- phases 1..3 ----------
#pragma unroll
    for (int p = 1; p < 4; ++p) {
      __builtin_amdgcn_sched_barrier(0);
      __builtin_amdgcn_s_barrier();
      __builtin_amdgcn_sched_barrier(0);
      if (notlast) {
        stageA(kt + 64, cur ^ 1, p);
        stageB(kt + 64, cur ^ 1, p);
      }
      bf16x8 af[2][2];
#pragma unroll
      for (int i = 0; i < 2; ++i)
#pragma unroll
        for (int ks = 0; ks < 2; ++ks)
          af[i][ks] = *(const bf16x8*)(&Al[cur][(((((wr * 8 + p * 2 + i) * 2) + ks) * 64 + l) * 8)]);
      __builtin_amdgcn_s_setprio(1);
#pragma unroll
      for (int ks = 0; ks < 2; ++ks)
#pragma unroll
        for (int i = 0; i < 2; ++i)
#pragma unroll
          for (int j = 0; j < 4; ++j)
            acc[p * 2 + i][j] = mfma16(af[i][ks], bfv[j][ks], acc[p * 2 + i][j]);
      __builtin_amdgcn_s_setprio(0);
    }

    // tile-end barrier: all waves done reading buf cur before t+2's staging overwrites it
    __builtin_amdgcn_sched_barrier(0);
    __builtin_amdgcn_s_barrier();
    __builtin_amdgcn_sched_barrier(0);
    cur ^= 1;
  }

  const int seg = colT >> 11;  // block-uniform (256 | 2048)
#pragma unroll
  for (int i = 0; i < 8; ++i) {
#pragma unroll
    for (int j = 0; j < 4; ++j) {
      const int col = colT + wc * 64 + j * 16 + lr;
#pragma unroll
      for (int e = 0; e < 4; ++e) {
        const int row = rowT + wr * 128 + i * 16 + lg * 4 + e;
        float v = acc[i][j][e];
        const int c = col & 2047;
        if (seg == 0)      Qo[(size_t)row * 2048 + c] = f2bf(v);
        else if (seg == 1) Ko[(size_t)row * 2048 + c] = f2bf(v);
        else               Vo[((size_t)((row >> 11) * 2048 + c)) * 2048 + (row & 2047)] = f2bf(v);
      }
    }
  }
}

// ======================= flash kernel: O + row stats (R13/R14) =======================
__global__ __launch_bounds__(256) void flash_kernel(const ushort* __restrict__ Qg,
                                                    const ushort* __restrict__ Kg,
                                                    const ushort* __restrict__ Vt,
                                                    ushort* __restrict__ Og,
                                                    float2* __restrict__ stats) {
  __shared__ __align__(16) ushort Kl[2][8192];
  __shared__ __align__(16) ushort Vl[2][8192];
  __shared__ __align__(16) ushort Pl[4][1024];

  // XCD-chunked swizzle: 512 blocks, 512%8==0
  const int flat = (int)(blockIdx.y * gridDim.x + blockIdx.x);
  const int swz = (flat & 7) * 64 + (flat >> 3);
  const int bx = swz & 15, bh = swz >> 4;
  const int b = bh >> 4, h = bh & 15;
  const int tid = (int)threadIdx.x, l = tid & 63, w = tid >> 6;
  const int lr = l & 15, lg = l >> 4;
  const float scale = 0.08838834764831845f;    // 1/sqrt(128)
  const float slope = exp2f(-(float)(h + 1));  // alibi slope
  const ushort* Kbase = Kg + ((size_t)b * 2048) * 2048 + h * 128;
  const ushort* Vbase = Vt + ((size_t)b * 2048 + h * 128) * 2048;

  for (int half = 0; half < 2; ++half) {
    const int qb = (half == 0) ? 31 - bx : bx;
    const int qr0 = qb * 64 + w * 16;

    bf16x8 qf[4];
#pragma unroll
    for (int ks = 0; ks < 4; ++ks)
      qf[ks] = *(const bf16x8*)(Qg + ((size_t)b * 2048 + qr0 + lr) * 2048 + h * 128 + ks * 32 + lg * 8);

    float runmax[4], runsum[4];
    f32x4 o[8] = {};
#pragma unroll
    for (int j = 0; j < 4; ++j) { runmax[j] = -__builtin_inff(); runsum[j] = 0.f; }

    auto stage = [&](int jt, int buf) {
#pragma unroll
      for (int q = 0; q < 4; ++q) {
        const int s = q * 256 + tid;
        const int sl = s & 63;
        const int cb = s >> 8, ks = (s >> 6) & 3;
        gl_lds16(Kbase + (size_t)(jt * 64 + cb * 16 + (sl & 15)) * 2048 + ks * 32 + (sl >> 4) * 8,
                 &Kl[buf][(size_t)(q * 256 + (tid & 192)) * 8]);
        const int db = s >> 7, k2 = (s >> 6) & 1;
        gl_lds16(Vbase + (size_t)(db * 16 + (sl & 15)) * 2048 + jt * 64 + k2 * 32 + (sl >> 4) * 8,
                 &Vl[buf][(size_t)(q * 256 + (tid & 192)) * 8]);
      }
    };

    stage(0, 0);  // prologue: 8 loads/wave in flight

    for (int jt = 0; jt <= qb; ++jt) {
      const int cur = jt & 1;
      if (jt < qb) {
        stage(jt + 1, cur ^ 1);                              // +8 loads (16 outstanding)
        asm volatile("s_waitcnt vmcnt(8)" ::: "memory");     // wait stage(jt) only
      } else {
        asm volatile("s_waitcnt vmcnt(0)" ::: "memory");     // last tile: full drain
      }
      __builtin_amdgcn_sched_barrier(0);
      __builtin_amdgcn_s_barrier();      // all waves' stage(jt) complete -> buf cur ready
      __builtin_amdgcn_sched_barrier(0);

      // QK^T + bias/mask
      f32x4 sc[4];
      __builtin_amdgcn_s_setprio(1);
#pragma unroll
      for (int cb = 0; cb < 4; ++cb) {
        f32x4 a = {};
#pragma unroll
        for (int ks = 0; ks < 4; ++ks) {
          bf16x8 kf = *(const bf16x8*)(&Kl[cur][((cb * 4 + ks) * 64 + l) * 8]);
          a = mfma16(qf[ks], kf, a);
        }
        sc[cb] = a;
      }
      __builtin_amdgcn_s_setprio(0);
#pragma unroll
      for (int cb = 0; cb < 4; ++cb) {
        const int kj = jt * 64 + cb * 16 + lr;
#pragma unroll
        for (int j = 0; j < 4; ++j) {
          const int qi = qr0 + lg * 4 + j;
          sc[cb][j] = (kj <= qi) ? sc[cb][j] * scale + slope * (float)(qi - kj) : -__builtin_inff();
        }
      }

      // deferred max: cheap per-lane growth check; full reduce+rescale only if needed
      float ml[4];
      bool grow = false;
#pragma unroll
      for (int j = 0; j < 4; ++j) {
        ml[j] = fmaxf(fmaxf(sc[0][j], sc[1][j]), fmaxf(sc[2][j], sc[3][j]));
        grow = grow || (ml[j] > runmax[j]);
      }
      if (__any(grow)) {
#pragma unroll
        for (int j = 0; j < 4; ++j) {
          float m = ml[j];
#pragma unroll
          for (int d = 1; d < 16; d <<= 1) m = fmaxf(m, __shfl_xor(m, d));
          const float nm = fmaxf(runmax[j], m);
          const float f = __expf(runmax[j] - nm);  // 0 on first tile, 1 if no growth
          runsum[j] *= f;
#pragma unroll
          for (int db = 0; db < 8; ++db) o[db][j] *= f;
          runmax[j] = nm;
        }
      }

      // p = exp(s - m); lane-partial row sums (reduced once at the end)
#pragma unroll
      for (int cb = 0; cb < 4; ++cb) {
        const int kc = cb * 16 + lr;
#pragma unroll
        for (int j = 0; j < 4; ++j) {
          const float p = __expf(sc[cb][j] - runmax[j]);
          runsum[j] += p;
          const int l2 = (((kc & 31) >> 3) << 4) | (lg * 4 + j);
          Pl[w][((kc >> 5) * 64 + l2) * 8 + (kc & 7)] = f2bf(p);
        }
      }

      // PV (P round-trips per-wave LDS into A-frag order; wave-local lgkmcnt)
      bf16x8 pf0 = *(const bf16x8*)(&Pl[w][(size_t)l * 8]);
      bf16x8 pf1 = *(const bf16x8*)(&Pl[w][(size_t)(64 + l) * 8]);
      __builtin_amdgcn_s_setprio(1);
#pragma unroll
      for (int db = 0; db < 8; ++db) {
        o[db] = mfma16(pf0, *(const bf16x8*)(&Vl[cur][((db * 2 + 0) * 64 + l) * 8]), o[db]);
        o[db] = mfma16(pf1, *(const bf16x8*)(&Vl[cur][((db * 2 + 1) * 64 + l) * 8]), o[db]);
      }
      __builtin_amdgcn_s_setprio(0);

      __builtin_amdgcn_sched_barrier(0);
      __builtin_amdgcn_s_barrier();      // all waves done reading buf cur before overwrite
      __builtin_amdgcn_sched_barrier(0);
    }

    // finalize: reduce row sums, write stats + O
#pragma unroll
    for (int j = 0; j < 4; ++j) {
      float s = runsum[j];
#pragma unroll
      for (int d = 1; d < 16; d <<= 1) s += __shfl_xor(s, d);
      const float iv = 1.0f / s;
      if (lr == 0) stats[(size_t)bh * 2048 + qr0 + lg * 4 + j] = make_float2(runmax[j], iv);
#pragma unroll
      for (int db = 0; db < 8; ++db) o[db][j] *= iv;
    }
#pragma unroll
    for (int db = 0; db < 8; ++db)
#pragma unroll
      for (int j = 0; j < 4; ++j)
        Og[((size_t)b * 2048 + qr0 + lg * 4 + j) * 2048 + h * 128 + db * 16 + lr] = f2bf(o[db][j]);
  }
}

// ======================= tail kernel: proj GEMM ∥ probs (R16 proven) =================
__global__ __launch_bounds__(256) void tail_kernel(const ushort* __restrict__ Ob,
                                                   const ushort* __restrict__ wob,
                                                   float* __restrict__ outp,
                                                   const float* __restrict__ bias,
                                                   const ushort* __restrict__ Qg,
                                                   const ushort* __restrict__ Kg,
                                                   const float2* __restrict__ stats,
                                                   float* __restrict__ attn_out) {
  __shared__ __align__(16) ushort SM[32768];  // 64 KB, shared by both paths
  const int blk = (int)blockIdx.x;
  const int tid = (int)threadIdx.x;
  const int l = tid & 63, w = tid >> 6;
  const int lr = l & 15, lg = l >> 4;

  if (blk < 512) {
    // ------- projection GEMM with graduated half-tile vmcnt (R14-identical)
    ushort (*Al)[8192] = (ushort(*)[8192])(SM);
    ushort (*Bl)[8192] = (ushort(*)[8192])(SM + 16384);
    const int wr = w >> 1, wc = w & 1;
    const int swz = (blk & 7) * 64 + (blk >> 3);  // 512 blocks, %8==0
    const int bx = swz & 15, by = swz >> 4;       // grid (16, 32)
    const int rowT = by * 128, colT = bx * 128;
    const int K = 2048;

    f32x4 acc[4][4] = {};

    auto stage = [&](int kt, int buf) {
#pragma unroll
      for (int ks = 0; ks < 2; ++ks) {
#pragma unroll
        for (int fg = 0; fg < 2; ++fg) {
          const int f = fg * 4 + w;
          const size_t koff = (size_t)(kt + ks * 32 + lg * 8);
          const int dst = ((f * 2 + ks) * 64) * 8;
          gl_lds16(Ob + (size_t)(rowT + f * 16 + lr) * K + koff, &Al[buf][dst]);
          gl_lds16(wob + (size_t)(colT + f * 16 + lr) * K + koff, &Bl[buf][dst]);
        }
      }
    };

    stage(0, 0);
    stage(64, 1);
    int cur = 0;
    for (int kt = 0; kt < K; kt += 64) {
      const bool notlast = (kt + 64 < K);
      if (notlast) asm volatile("s_waitcnt vmcnt(12)" ::: "memory");
      else         asm volatile("s_waitcnt vmcnt(4)" ::: "memory");
      __builtin_amdgcn_sched_barrier(0);
      __builtin_amdgcn_s_barrier();
      __builtin_amdgcn_sched_barrier(0);
      {
        bf16x8 af[4], bfv[4];
#pragma unroll
        for (int i = 0; i < 4; ++i) {
          af[i]  = *(const bf16x8*)(&Al[cur][(((wr * 4 + i) * 2 + 0) * 64 + l) * 8]);
          bfv[i] = *(const bf16x8*)(&Bl[cur][(((wc * 4 + i) * 2 + 0) * 64 + l) * 8]);
        }
        __builtin_amdgcn_s_setprio(1);
#pragma unroll
        for (int i = 0; i < 4; ++i)
#pragma unroll
          for (int j = 0; j < 4; ++j)
            acc[i][j] = mfma16(af[i], bfv[j], acc[i][j]);
        __builtin_amdgcn_s_setprio(0);
      }
      if (notlast) asm volatile("s_waitcnt vmcnt(8)" ::: "memory");
      else         asm volatile("s_waitcnt vmcnt(0)" ::: "memory");
      __builtin_amdgcn_sched_barrier(0);
      __builtin_amdgcn_s_barrier();
      __builtin_amdgcn_sched_barrier(0);
      {
        bf16x8 af[4], bfv[4];
#pragma unroll
        for (int i = 0; i < 4; ++i) {
          af[i]  = *(const bf16x8*)(&Al[cur][(((wr * 4 + i) * 2 + 1) * 64 + l) * 8]);
          bfv[i] = *(const bf16x8*)(&Bl[cur][(((wc * 4 + i) * 2 + 1) * 64 + l) * 8]);
        }
        __builtin_amdgcn_s_setprio(1);
#pragma unroll
        for (int i = 0; i < 4; ++i)
#pragma unroll
          for (int j = 0; j < 4; ++j)
            acc[i][j] = mfma16(af[i], bfv[j], acc[i][j]);
        __builtin_amdgcn_s_setprio(0);
      }
      __builtin_amdgcn_sched_barrier(0);
      __builtin_amdgcn_s_barrier();
      __builtin_amdgcn_sched_barrier(0);
      if (kt + 128 < K) stage(kt + 128, cur);
      cur ^= 1;
    }

#pragma unroll
    for (int i = 0; i < 4; ++i) {
#pragma unroll
      for (int j = 0; j < 4; ++j) {
        const int col = colT + wc * 64 + j * 16 + lr;
#pragma unroll
        for (int e = 0; e < 4; ++e) {
          const int row = rowT + wr * 64 + i * 16 + lg * 4 + e;
          __builtin_nontemporal_store(acc[i][j][e] + bias[col],
                                      &outp[(size_t)row * 2048 + col]);
        }
      }
    }
    return;
  }

  // ---------------- probs path: blocks 512.. map to (kb, qb, bh)
  const int rem = blk - 512;
  const int kb = rem & 15, qb = (rem >> 4) & 15, bh = rem >> 8;

  if (kb > qb) {  // strictly-above-diagonal tile: exact zeros (512B segments)
    float* base = attn_out + ((size_t)bh * 2048 + qb * 128) * 2048 + kb * 128;
    const f32x4 z = {0.f, 0.f, 0.f, 0.f};
#pragma unroll
    for (int it = 0; it < 16; ++it) {
      const int idx = it * 256 + tid;
      __builtin_nontemporal_store(z, (f32x4*)(base + (size_t)(idx >> 5) * 2048 + (idx & 31) * 4));
    }
    return;
  }

  ushort* Ql = SM;
  ushort* Kl = SM + 16384;
  float* Pf = (float*)SM;  // reused after Q/K are consumed
  const int b = bh >> 4, h = bh & 15;
  const int wr = w >> 1, wc = w & 1;
  const float scale = 0.08838834764831845f;
  const float slope = exp2f(-(float)(h + 1));

#pragma unroll
  for (int q = 0; q < 8; ++q) {
    const int s = q * 256 + tid;
    const int sl = s & 63, rb = s >> 8, ks = (s >> 6) & 3;
    const size_t koff = (size_t)(h * 128 + ks * 32 + (sl >> 4) * 8);
    gl_lds16(Qg + ((size_t)b * 2048 + qb * 128 + rb * 16 + (sl & 15)) * 2048 + koff,
             Ql + (size_t)(q * 256 + (tid & 192)) * 8);
    gl_lds16(Kg + ((size_t)b * 2048 + kb * 128 + rb * 16 + (sl & 15)) * 2048 + koff,
             Kl + (size_t)(q * 256 + (tid & 192)) * 8);
  }
  __syncthreads();

  f32x4 acc[4][4] = {};
#pragma unroll
  for (int ks = 0; ks < 4; ++ks) {
    bf16x8 af[4], bfv[4];
#pragma unroll
    for (int i = 0; i < 4; ++i) {
      af[i]  = *(const bf16x8*)(Ql + (((wr * 4 + i) * 4 + ks) * 64 + l) * 8);
      bfv[i] = *(const bf16x8*)(Kl + (((wc * 4 + i) * 4 + ks) * 64 + l) * 8);
    }
#pragma unroll
    for (int i = 0; i < 4; ++i)
#pragma unroll
      for (int j = 0; j < 4; ++j)
        acc[i][j] = mfma16(af[i], bfv[j], acc[i][j]);
  }

  float2 st[4][4];
#pragma unroll
  for (int i = 0; i < 4; ++i)
#pragma unroll
    for (int e = 0; e < 4; ++e)
      st[i][e] = stats[(size_t)bh * 2048 + qb * 128 + wr * 64 + i * 16 + lg * 4 + e];

  __syncthreads();  // all waves' Q/K ds_reads consumed -> safe to overwrite SM with P

#pragma unroll
  for (int i = 0; i < 4; ++i) {
#pragma unroll
    for (int j = 0; j < 4; ++j) {
      const int cl = wc * 64 + j * 16 + lr;   // local key col
      const int kj = kb * 128 + cl;
#pragma unroll
      for (int e = 0; e < 4; ++e) {
        const int rl = wr * 64 + i * 16 + lg * 4 + e;  // local query row
        const int qi = qb * 128 + rl;
        const float sv = acc[i][j][e] * scale + slope * (float)(qi - kj);
        float p = __expf(sv - st[i][e].x) * st[i][e].y;
        if (kj > qi) p = 0.f;  // only possible when kb == qb
        Pf[rl * 128 + ((cl + (rl << 2)) & 127)] = p;  // row-rotation: 2-way max conflict
      }
    }
  }
  __syncthreads();

  float* gbase = attn_out + ((size_t)bh * 2048 + qb * 128) * 2048 + kb * 128;
#pragma unroll
  for (int it = 0; it < 16; ++it) {
    const int idx = it * 256 + tid;
    const int row = idx >> 5, c4 = (idx & 31) << 2;
    f32x4 v = *(const f32x4*)(&Pf[row * 128 + ((c4 + (row << 2)) & 127)]);
    __builtin_nontemporal_store(v, (f32x4*)(gbase + (size_t)row * 2048 + c4));
  }
}

// ======================= launch =======================
extern "C" void kernel_launch(void* const* d_in, const int* in_sizes, int n_in,
                              void* d_out, int out_size, void* d_ws, size_t ws_size,
                              hipStream_t stream) {
  (void)in_sizes; (void)n_in; (void)out_size; (void)ws_size;
  const float* x  = (const float*)d_in[0];
  const float* Wq = (const float*)d_in[1];
  const float* Wk = (const float*)d_in[2];
  const float* Wv = (const float*)d_in[3];
  const float* Wo = (const float*)d_in[4];
  const float* bo = (const float*)d_in[5];

  float* outp  = (float*)d_out;                      // (B,T,C) f32
  float* attnp = outp + (size_t)4096 * 2048;         // (B,H,T,T) f32

  char* ws = (char*)d_ws;                            // 112 MB used
  ushort* xb   = (ushort*)(ws);                      // x bf16              (16 MB)
  ushort* wqkv = (ushort*)(ws + (16ull << 20));      // [Wq;Wk;Wv] bf16     (24 MB)
  ushort* wob  = (ushort*)(ws + (40ull << 20));      // Wo bf16             (8 MB)
  ushort* Qb   = (ushort*)(ws + (48ull << 20));      // Q bf16              (16 MB)
  ushort* Kb   = (ushort*)(ws + (64ull << 20));      // K bf16              (16 MB)
  ushort* Vtb  = (ushort*)(ws + (80ull << 20));      // V^T bf16            (16 MB)
  ushort* Ob   = (ushort*)(ws + (96ull << 20));      // attn@V bf16         (16 MB)
  // stats (m, 1/sum) per row: 512 KB. Reuses xb (dead after QKV GEMM, recast each call).
  float2* stats = (float2*)(ws);

  cast_all_kernel<<<6144, 256, 0, stream>>>(
      (const float4*)x, (const float4*)Wq, (const float4*)Wk, (const float4*)Wv,
      (const float4*)Wo, (ushort4*)xb, (ushort4*)wqkv, (ushort4*)(wqkv + 4194304),
      (ushort4*)(wqkv + 2 * 4194304), (ushort4*)wob);

  // fused QKV: M=4096, N=6144, K=2048 — 256^2 tiles, 4-phase interleaved schedule
  gemm_qkv<<<dim3(24, 16), 512, 0, stream>>>(xb, wqkv, Qb, Kb, Vtb, 4096, 6144, 2048);

  flash_kernel<<<dim3(16, 32), 256, 0, stream>>>(Qb, Kb, Vtb, Ob, stats);

  // merged tail: 512 proj blocks + 8192 probs blocks
  tail_kernel<<<8704, 256, 0, stream>>>(Ob, wob, outp, bo, Qb, Kb, stats, attnp);
}

// Round 18
// 501.409 us; speedup vs baseline: 1.1308x; 1.1308x over previous
//
#include <hip/hip_runtime.h>
#include <hip/hip_bf16.h>

#define DEVINL __device__ __forceinline__

typedef __attribute__((ext_vector_type(8))) short bf16x8;
typedef __attribute__((ext_vector_type(4))) float f32x4;

// f32 -> bf16 round-nearest-even (bit manipulation; values are finite)
DEVINL ushort f2bf(float f) {
  unsigned u = __float_as_uint(f);
  u += 0x7fffu + ((u >> 16) & 1u);
  return (ushort)(u >> 16);
}

DEVINL void gl_lds16(const void* g, void* lds) {
  __builtin_amdgcn_global_load_lds(
      (const __attribute__((address_space(1))) void*)g,
      (__attribute__((address_space(3))) void*)lds, 16, 0, 0);
}

DEVINL f32x4 mfma16(bf16x8 a, bf16x8 b, f32x4 c) {
  return __builtin_amdgcn_mfma_f32_16x16x32_bf16(a, b, c, 0, 0, 0);
}

// ======================= fused cast f32 -> bf16 (exact shapes) =======================
__global__ __launch_bounds__(256) void cast_all_kernel(const float4* __restrict__ x,
                                                       const float4* __restrict__ wq,
                                                       const float4* __restrict__ wk,
                                                       const float4* __restrict__ wv,
                                                       const float4* __restrict__ wo,
                                                       ushort4* __restrict__ xb,
                                                       ushort4* __restrict__ wqb,
                                                       ushort4* __restrict__ wkb,
                                                       ushort4* __restrict__ wvb,
                                                       ushort4* __restrict__ wob) {
  const int blk = (int)blockIdx.x;
  const float4* src;
  ushort4* dst;
  int base;
  if (blk < 2048)      { src = x;  dst = xb;  base = blk; }
  else if (blk < 3072) { src = wq; dst = wqb; base = blk - 2048; }
  else if (blk < 4096) { src = wk; dst = wkb; base = blk - 3072; }
  else if (blk < 5120) { src = wv; dst = wvb; base = blk - 4096; }
  else                 { src = wo; dst = wob; base = blk - 5120; }
  const int idx0 = base * 1024 + (int)threadIdx.x;
#pragma unroll
  for (int i = 0; i < 4; ++i) {
    const int idx = idx0 + i * 256;
    float4 v = src[idx];
    dst[idx] = make_ushort4(f2bf(v.x), f2bf(v.y), f2bf(v.z), f2bf(v.w));
  }
}

// ======================= QKV GEMM: 128^2 tile, graduated half-tile vmcnt (R14) ========
__global__ __launch_bounds__(256) void gemm_qkv(const ushort* __restrict__ A,
                                                const ushort* __restrict__ Bm,
                                                ushort* __restrict__ Qo,
                                                ushort* __restrict__ Ko,
                                                ushort* __restrict__ Vo,
                                                int M, int N, int K) {
  __shared__ __align__(16) ushort Al[2][8192];  // [f:8][ks:2][lane:64][8]
  __shared__ __align__(16) ushort Bl[2][8192];
  const int tid = (int)threadIdx.x;
  const int l = tid & 63, w = tid >> 6;
  const int wr = w >> 1, wc = w & 1;
  const int lr = l & 15, lg = l >> 4;

  // bijective XCD-chunked swizzle (nwg % 8 == 0)
  const int nwg = (int)(gridDim.x * gridDim.y);
  const int flat = (int)(blockIdx.y * gridDim.x + blockIdx.x);
  const int swz = (flat & 7) * (nwg >> 3) + (flat >> 3);
  const int bx = swz % (int)gridDim.x, by = swz / (int)gridDim.x;
  const int rowT = by * 128, colT = bx * 128;

  f32x4 acc[4][4] = {};

  // wave w stages slice f = fg*4 + w for each (ks, fg); 8 instr/thread per tile
  auto stage = [&](int kt, int buf) {
#pragma unroll
    for (int ks = 0; ks < 2; ++ks) {
#pragma unroll
      for (int fg = 0; fg < 2; ++fg) {
        const int f = fg * 4 + w;
        const size_t koff = (size_t)(kt + ks * 32 + lg * 8);
        const int dst = ((f * 2 + ks) * 64) * 8;  // wave-uniform LDS base
        gl_lds16(A + (size_t)(rowT + f * 16 + lr) * K + koff, &Al[buf][dst]);
        gl_lds16(Bm + (size_t)(colT + f * 16 + lr) * K + koff, &Bl[buf][dst]);
      }
    }
  };

  stage(0, 0);
  stage(64, 1);
  int cur = 0;
  for (int kt = 0; kt < K; kt += 64) {
    const bool notlast = (kt + 64 < K);
    // ---- phase ks = 0 ----
    if (notlast) asm volatile("s_waitcnt vmcnt(12)" ::: "memory");
    else         asm volatile("s_waitcnt vmcnt(4)" ::: "memory");
    __builtin_amdgcn_sched_barrier(0);
    __builtin_amdgcn_s_barrier();
    __builtin_amdgcn_sched_barrier(0);
    {
      bf16x8 af[4], bfv[4];
#pragma unroll
      for (int i = 0; i < 4; ++i) {
        af[i]  = *(const bf16x8*)(&Al[cur][(((wr * 4 + i) * 2 + 0) * 64 + l) * 8]);
        bfv[i] = *(const bf16x8*)(&Bl[cur][(((wc * 4 + i) * 2 + 0) * 64 + l) * 8]);
      }
      __builtin_amdgcn_s_setprio(1);
#pragma unroll
      for (int i = 0; i < 4; ++i)
#pragma unroll
        for (int j = 0; j < 4; ++j)
          acc[i][j] = mfma16(af[i], bfv[j], acc[i][j]);
      __builtin_amdgcn_s_setprio(0);
    }
    // ---- phase ks = 1 ----
    if (notlast) asm volatile("s_waitcnt vmcnt(8)" ::: "memory");
    else         asm volatile("s_waitcnt vmcnt(0)" ::: "memory");
    __builtin_amdgcn_sched_barrier(0);
    __builtin_amdgcn_s_barrier();
    __builtin_amdgcn_sched_barrier(0);
    {
      bf16x8 af[4], bfv[4];
#pragma unroll
      for (int i = 0; i < 4; ++i) {
        af[i]  = *(const bf16x8*)(&Al[cur][(((wr * 4 + i) * 2 + 1) * 64 + l) * 8]);
        bfv[i] = *(const bf16x8*)(&Bl[cur][(((wc * 4 + i) * 2 + 1) * 64 + l) * 8]);
      }
      __builtin_amdgcn_s_setprio(1);
#pragma unroll
      for (int i = 0; i < 4; ++i)
#pragma unroll
        for (int j = 0; j < 4; ++j)
          acc[i][j] = mfma16(af[i], bfv[j], acc[i][j]);
      __builtin_amdgcn_s_setprio(0);
    }
    __builtin_amdgcn_sched_barrier(0);
    __builtin_amdgcn_s_barrier();
    __builtin_amdgcn_sched_barrier(0);
    if (kt + 128 < K) stage(kt + 128, cur);
    cur ^= 1;
  }

  const int seg = colT >> 11;  // block-uniform
#pragma unroll
  for (int i = 0; i < 4; ++i) {
#pragma unroll
    for (int j = 0; j < 4; ++j) {
      const int col = colT + wc * 64 + j * 16 + lr;
#pragma unroll
      for (int e = 0; e < 4; ++e) {
        const int row = rowT + wr * 64 + i * 16 + lg * 4 + e;
        float v = acc[i][j][e];
        const int c = col & 2047;
        if (seg == 0)      Qo[(size_t)row * 2048 + c] = f2bf(v);
        else if (seg == 1) Ko[(size_t)row * 2048 + c] = f2bf(v);
        else               Vo[((size_t)((row >> 11) * 2048 + c)) * 2048 + (row & 2047)] = f2bf(v);
      }
    }
  }
}

// ======================= flash kernel: O + row stats (R13/R14) =======================
__global__ __launch_bounds__(256) void flash_kernel(const ushort* __restrict__ Qg,
                                                    const ushort* __restrict__ Kg,
                                                    const ushort* __restrict__ Vt,
                                                    ushort* __restrict__ Og,
                                                    float2* __restrict__ stats) {
  __shared__ __align__(16) ushort Kl[2][8192];
  __shared__ __align__(16) ushort Vl[2][8192];
  __shared__ __align__(16) ushort Pl[4][1024];

  // XCD-chunked swizzle: 512 blocks, 512%8==0
  const int flat = (int)(blockIdx.y * gridDim.x + blockIdx.x);
  const int swz = (flat & 7) * 64 + (flat >> 3);
  const int bx = swz & 15, bh = swz >> 4;
  const int b = bh >> 4, h = bh & 15;
  const int tid = (int)threadIdx.x, l = tid & 63, w = tid >> 6;
  const int lr = l & 15, lg = l >> 4;
  const float scale = 0.08838834764831845f;    // 1/sqrt(128)
  const float slope = exp2f(-(float)(h + 1));  // alibi slope
  const ushort* Kbase = Kg + ((size_t)b * 2048) * 2048 + h * 128;
  const ushort* Vbase = Vt + ((size_t)b * 2048 + h * 128) * 2048;

  for (int half = 0; half < 2; ++half) {
    const int qb = (half == 0) ? 31 - bx : bx;
    const int qr0 = qb * 64 + w * 16;

    bf16x8 qf[4];
#pragma unroll
    for (int ks = 0; ks < 4; ++ks)
      qf[ks] = *(const bf16x8*)(Qg + ((size_t)b * 2048 + qr0 + lr) * 2048 + h * 128 + ks * 32 + lg * 8);

    float runmax[4], runsum[4];
    f32x4 o[8] = {};
#pragma unroll
    for (int j = 0; j < 4; ++j) { runmax[j] = -__builtin_inff(); runsum[j] = 0.f; }

    auto stage = [&](int jt, int buf) {
#pragma unroll
      for (int q = 0; q < 4; ++q) {
        const int s = q * 256 + tid;
        const int sl = s & 63;
        const int cb = s >> 8, ks = (s >> 6) & 3;
        gl_lds16(Kbase + (size_t)(jt * 64 + cb * 16 + (sl & 15)) * 2048 + ks * 32 + (sl >> 4) * 8,
                 &Kl[buf][(size_t)(q * 256 + (tid & 192)) * 8]);
        const int db = s >> 7, k2 = (s >> 6) & 1;
        gl_lds16(Vbase + (size_t)(db * 16 + (sl & 15)) * 2048 + jt * 64 + k2 * 32 + (sl >> 4) * 8,
                 &Vl[buf][(size_t)(q * 256 + (tid & 192)) * 8]);
      }
    };

    stage(0, 0);  // prologue: 8 loads/wave in flight

    for (int jt = 0; jt <= qb; ++jt) {
      const int cur = jt & 1;
      if (jt < qb) {
        stage(jt + 1, cur ^ 1);                              // +8 loads (16 outstanding)
        asm volatile("s_waitcnt vmcnt(8)" ::: "memory");     // wait stage(jt) only
      } else {
        asm volatile("s_waitcnt vmcnt(0)" ::: "memory");     // last tile: full drain
      }
      __builtin_amdgcn_sched_barrier(0);
      __builtin_amdgcn_s_barrier();      // all waves' stage(jt) complete -> buf cur ready
      __builtin_amdgcn_sched_barrier(0);

      // QK^T + bias/mask
      f32x4 sc[4];
      __builtin_amdgcn_s_setprio(1);
#pragma unroll
      for (int cb = 0; cb < 4; ++cb) {
        f32x4 a = {};
#pragma unroll
        for (int ks = 0; ks < 4; ++ks) {
          bf16x8 kf = *(const bf16x8*)(&Kl[cur][((cb * 4 + ks) * 64 + l) * 8]);
          a = mfma16(qf[ks], kf, a);
        }
        sc[cb] = a;
      }
      __builtin_amdgcn_s_setprio(0);
#pragma unroll
      for (int cb = 0; cb < 4; ++cb) {
        const int kj = jt * 64 + cb * 16 + lr;
#pragma unroll
        for (int j = 0; j < 4; ++j) {
          const int qi = qr0 + lg * 4 + j;
          sc[cb][j] = (kj <= qi) ? sc[cb][j] * scale + slope * (float)(qi - kj) : -__builtin_inff();
        }
      }

      // deferred max: cheap per-lane growth check; full reduce+rescale only if needed
      float ml[4];
      bool grow = false;
#pragma unroll
      for (int j = 0; j < 4; ++j) {
        ml[j] = fmaxf(fmaxf(sc[0][j], sc[1][j]), fmaxf(sc[2][j], sc[3][j]));
        grow = grow || (ml[j] > runmax[j]);
      }
      if (__any(grow)) {
#pragma unroll
        for (int j = 0; j < 4; ++j) {
          float m = ml[j];
#pragma unroll
          for (int d = 1; d < 16; d <<= 1) m = fmaxf(m, __shfl_xor(m, d));
          const float nm = fmaxf(runmax[j], m);
          const float f = __expf(runmax[j] - nm);  // 0 on first tile, 1 if no growth
          runsum[j] *= f;
#pragma unroll
          for (int db = 0; db < 8; ++db) o[db][j] *= f;
          runmax[j] = nm;
        }
      }

      // p = exp(s - m); lane-partial row sums (reduced once at the end)
#pragma unroll
      for (int cb = 0; cb < 4; ++cb) {
        const int kc = cb * 16 + lr;
#pragma unroll
        for (int j = 0; j < 4; ++j) {
          const float p = __expf(sc[cb][j] - runmax[j]);
          runsum[j] += p;
          const int l2 = (((kc & 31) >> 3) << 4) | (lg * 4 + j);
          Pl[w][((kc >> 5) * 64 + l2) * 8 + (kc & 7)] = f2bf(p);
        }
      }

      // PV (P round-trips per-wave LDS into A-frag order; wave-local lgkmcnt)
      bf16x8 pf0 = *(const bf16x8*)(&Pl[w][(size_t)l * 8]);
      bf16x8 pf1 = *(const bf16x8*)(&Pl[w][(size_t)(64 + l) * 8]);
      __builtin_amdgcn_s_setprio(1);
#pragma unroll
      for (int db = 0; db < 8; ++db) {
        o[db] = mfma16(pf0, *(const bf16x8*)(&Vl[cur][((db * 2 + 0) * 64 + l) * 8]), o[db]);
        o[db] = mfma16(pf1, *(const bf16x8*)(&Vl[cur][((db * 2 + 1) * 64 + l) * 8]), o[db]);
      }
      __builtin_amdgcn_s_setprio(0);

      __builtin_amdgcn_sched_barrier(0);
      __builtin_amdgcn_s_barrier();      // all waves done reading buf cur before overwrite
      __builtin_amdgcn_sched_barrier(0);
    }

    // finalize: reduce row sums, write stats + O
#pragma unroll
    for (int j = 0; j < 4; ++j) {
      float s = runsum[j];
#pragma unroll
      for (int d = 1; d < 16; d <<= 1) s += __shfl_xor(s, d);
      const float iv = 1.0f / s;
      if (lr == 0) stats[(size_t)bh * 2048 + qr0 + lg * 4 + j] = make_float2(runmax[j], iv);
#pragma unroll
      for (int db = 0; db < 8; ++db) o[db][j] *= iv;
    }
#pragma unroll
    for (int db = 0; db < 8; ++db)
#pragma unroll
      for (int j = 0; j < 4; ++j)
        Og[((size_t)b * 2048 + qr0 + lg * 4 + j) * 2048 + h * 128 + db * 16 + lr] = f2bf(o[db][j]);
  }
}

// ======================= tail kernel: proj GEMM ∥ probs (R16 proven) =================
// Blocks [0,512): projection GEMM (R14 graduated-vmcnt). Blocks [512,8704): probs tiles.
// probs epilogue routes P through the dead Q/K LDS (row-rotation layout, 2-way max bank
// conflict = free) so global NT stores become f32x4 with 512B-contiguous row segments.
__global__ __launch_bounds__(256) void tail_kernel(const ushort* __restrict__ Ob,
                                                   const ushort* __restrict__ wob,
                                                   float* __restrict__ outp,
                                                   const float* __restrict__ bias,
                                                   const ushort* __restrict__ Qg,
                                                   const ushort* __restrict__ Kg,
                                                   const float2* __restrict__ stats,
                                                   float* __restrict__ attn_out) {
  __shared__ __align__(16) ushort SM[32768];  // 64 KB, shared by both paths
  const int blk = (int)blockIdx.x;
  const int tid = (int)threadIdx.x;
  const int l = tid & 63, w = tid >> 6;
  const int lr = l & 15, lg = l >> 4;

  if (blk < 512) {
    // ------- projection GEMM with graduated half-tile vmcnt (R14-identical)
    ushort (*Al)[8192] = (ushort(*)[8192])(SM);
    ushort (*Bl)[8192] = (ushort(*)[8192])(SM + 16384);
    const int wr = w >> 1, wc = w & 1;
    const int swz = (blk & 7) * 64 + (blk >> 3);  // 512 blocks, %8==0
    const int bx = swz & 15, by = swz >> 4;       // grid (16, 32)
    const int rowT = by * 128, colT = bx * 128;
    const int K = 2048;

    f32x4 acc[4][4] = {};

    auto stage = [&](int kt, int buf) {
#pragma unroll
      for (int ks = 0; ks < 2; ++ks) {
#pragma unroll
        for (int fg = 0; fg < 2; ++fg) {
          const int f = fg * 4 + w;
          const size_t koff = (size_t)(kt + ks * 32 + lg * 8);
          const int dst = ((f * 2 + ks) * 64) * 8;
          gl_lds16(Ob + (size_t)(rowT + f * 16 + lr) * K + koff, &Al[buf][dst]);
          gl_lds16(wob + (size_t)(colT + f * 16 + lr) * K + koff, &Bl[buf][dst]);
        }
      }
    };

    stage(0, 0);
    stage(64, 1);
    int cur = 0;
    for (int kt = 0; kt < K; kt += 64) {
      const bool notlast = (kt + 64 < K);
      if (notlast) asm volatile("s_waitcnt vmcnt(12)" ::: "memory");
      else         asm volatile("s_waitcnt vmcnt(4)" ::: "memory");
      __builtin_amdgcn_sched_barrier(0);
      __builtin_amdgcn_s_barrier();
      __builtin_amdgcn_sched_barrier(0);
      {
        bf16x8 af[4], bfv[4];
#pragma unroll
        for (int i = 0; i < 4; ++i) {
          af[i]  = *(const bf16x8*)(&Al[cur][(((wr * 4 + i) * 2 + 0) * 64 + l) * 8]);
          bfv[i] = *(const bf16x8*)(&Bl[cur][(((wc * 4 + i) * 2 + 0) * 64 + l) * 8]);
        }
        __builtin_amdgcn_s_setprio(1);
#pragma unroll
        for (int i = 0; i < 4; ++i)
#pragma unroll
          for (int j = 0; j < 4; ++j)
            acc[i][j] = mfma16(af[i], bfv[j], acc[i][j]);
        __builtin_amdgcn_s_setprio(0);
      }
      if (notlast) asm volatile("s_waitcnt vmcnt(8)" ::: "memory");
      else         asm volatile("s_waitcnt vmcnt(0)" ::: "memory");
      __builtin_amdgcn_sched_barrier(0);
      __builtin_amdgcn_s_barrier();
      __builtin_amdgcn_sched_barrier(0);
      {
        bf16x8 af[4], bfv[4];
#pragma unroll
        for (int i = 0; i < 4; ++i) {
          af[i]  = *(const bf16x8*)(&Al[cur][(((wr * 4 + i) * 2 + 1) * 64 + l) * 8]);
          bfv[i] = *(const bf16x8*)(&Bl[cur][(((wc * 4 + i) * 2 + 1) * 64 + l) * 8]);
        }
        __builtin_amdgcn_s_setprio(1);
#pragma unroll
        for (int i = 0; i < 4; ++i)
#pragma unroll
          for (int j = 0; j < 4; ++j)
            acc[i][j] = mfma16(af[i], bfv[j], acc[i][j]);
        __builtin_amdgcn_s_setprio(0);
      }
      __builtin_amdgcn_sched_barrier(0);
      __builtin_amdgcn_s_barrier();
      __builtin_amdgcn_sched_barrier(0);
      if (kt + 128 < K) stage(kt + 128, cur);
      cur ^= 1;
    }

#pragma unroll
    for (int i = 0; i < 4; ++i) {
#pragma unroll
      for (int j = 0; j < 4; ++j) {
        const int col = colT + wc * 64 + j * 16 + lr;
#pragma unroll
        for (int e = 0; e < 4; ++e) {
          const int row = rowT + wr * 64 + i * 16 + lg * 4 + e;
          __builtin_nontemporal_store(acc[i][j][e] + bias[col],
                                      &outp[(size_t)row * 2048 + col]);
        }
      }
    }
    return;
  }

  // ---------------- probs path: blocks 512.. map to (kb, qb, bh)
  const int rem = blk - 512;
  const int kb = rem & 15, qb = (rem >> 4) & 15, bh = rem >> 8;

  if (kb > qb) {  // strictly-above-diagonal tile: exact zeros (512B segments)
    float* base = attn_out + ((size_t)bh * 2048 + qb * 128) * 2048 + kb * 128;
    const f32x4 z = {0.f, 0.f, 0.f, 0.f};
#pragma unroll
    for (int it = 0; it < 16; ++it) {
      const int idx = it * 256 + tid;
      __builtin_nontemporal_store(z, (f32x4*)(base + (size_t)(idx >> 5) * 2048 + (idx & 31) * 4));
    }
    return;
  }

  ushort* Ql = SM;
  ushort* Kl = SM + 16384;
  float* Pf = (float*)SM;  // reused after Q/K are consumed
  const int b = bh >> 4, h = bh & 15;
  const int wr = w >> 1, wc = w & 1;
  const float scale = 0.08838834764831845f;
  const float slope = exp2f(-(float)(h + 1));

#pragma unroll
  for (int q = 0; q < 8; ++q) {
    const int s = q * 256 + tid;
    const int sl = s & 63, rb = s >> 8, ks = (s >> 6) & 3;
    const size_t koff = (size_t)(h * 128 + ks * 32 + (sl >> 4) * 8);
    gl_lds16(Qg + ((size_t)b * 2048 + qb * 128 + rb * 16 + (sl & 15)) * 2048 + koff,
             Ql + (size_t)(q * 256 + (tid & 192)) * 8);
    gl_lds16(Kg + ((size_t)b * 2048 + kb * 128 + rb * 16 + (sl & 15)) * 2048 + koff,
             Kl + (size_t)(q * 256 + (tid & 192)) * 8);
  }
  __syncthreads();

  f32x4 acc[4][4] = {};
#pragma unroll
  for (int ks = 0; ks < 4; ++ks) {
    bf16x8 af[4], bfv[4];
#pragma unroll
    for (int i = 0; i < 4; ++i) {
      af[i]  = *(const bf16x8*)(Ql + (((wr * 4 + i) * 4 + ks) * 64 + l) * 8);
      bfv[i] = *(const bf16x8*)(Kl + (((wc * 4 + i) * 4 + ks) * 64 + l) * 8);
    }
#pragma unroll
    for (int i = 0; i < 4; ++i)
#pragma unroll
      for (int j = 0; j < 4; ++j)
        acc[i][j] = mfma16(af[i], bfv[j], acc[i][j]);
  }

  float2 st[4][4];
#pragma unroll
  for (int i = 0; i < 4; ++i)
#pragma unroll
    for (int e = 0; e < 4; ++e)
      st[i][e] = stats[(size_t)bh * 2048 + qb * 128 + wr * 64 + i * 16 + lg * 4 + e];

  __syncthreads();  // all waves' Q/K ds_reads consumed -> safe to overwrite SM with P

#pragma unroll
  for (int i = 0; i < 4; ++i) {
#pragma unroll
    for (int j = 0; j < 4; ++j) {
      const int cl = wc * 64 + j * 16 + lr;   // local key col
      const int kj = kb * 128 + cl;
#pragma unroll
      for (int e = 0; e < 4; ++e) {
        const int rl = wr * 64 + i * 16 + lg * 4 + e;  // local query row
        const int qi = qb * 128 + rl;
        const float sv = acc[i][j][e] * scale + slope * (float)(qi - kj);
        float p = __expf(sv - st[i][e].x) * st[i][e].y;
        if (kj > qi) p = 0.f;  // only possible when kb == qb
        Pf[rl * 128 + ((cl + (rl << 2)) & 127)] = p;  // row-rotation: 2-way max conflict
      }
    }
  }
  __syncthreads();

  float* gbase = attn_out + ((size_t)bh * 2048 + qb * 128) * 2048 + kb * 128;
#pragma unroll
  for (int it = 0; it < 16; ++it) {
    const int idx = it * 256 + tid;
    const int row = idx >> 5, c4 = (idx & 31) << 2;
    f32x4 v = *(const f32x4*)(&Pf[row * 128 + ((c4 + (row << 2)) & 127)]);
    __builtin_nontemporal_store(v, (f32x4*)(gbase + (size_t)row * 2048 + c4));
  }
}

// ======================= launch =======================
extern "C" void kernel_launch(void* const* d_in, const int* in_sizes, int n_in,
                              void* d_out, int out_size, void* d_ws, size_t ws_size,
                              hipStream_t stream) {
  (void)in_sizes; (void)n_in; (void)out_size; (void)ws_size;
  const float* x  = (const float*)d_in[0];
  const float* Wq = (const float*)d_in[1];
  const float* Wk = (const float*)d_in[2];
  const float* Wv = (const float*)d_in[3];
  const float* Wo = (const float*)d_in[4];
  const float* bo = (const float*)d_in[5];

  float* outp  = (float*)d_out;                      // (B,T,C) f32
  float* attnp = outp + (size_t)4096 * 2048;         // (B,H,T,T) f32

  char* ws = (char*)d_ws;                            // 112 MB used
  ushort* xb   = (ushort*)(ws);                      // x bf16              (16 MB)
  ushort* wqkv = (ushort*)(ws + (16ull << 20));      // [Wq;Wk;Wv] bf16     (24 MB)
  ushort* wob  = (ushort*)(ws + (40ull << 20));      // Wo bf16             (8 MB)
  ushort* Qb   = (ushort*)(ws + (48ull << 20));      // Q bf16              (16 MB)
  ushort* Kb   = (ushort*)(ws + (64ull << 20));      // K bf16              (16 MB)
  ushort* Vtb  = (ushort*)(ws + (80ull << 20));      // V^T bf16            (16 MB)
  ushort* Ob   = (ushort*)(ws + (96ull << 20));      // attn@V bf16         (16 MB)
  // stats (m, 1/sum) per row: 512 KB. Reuses xb (dead after QKV GEMM, recast each call).
  float2* stats = (float2*)(ws);

  cast_all_kernel<<<6144, 256, 0, stream>>>(
      (const float4*)x, (const float4*)Wq, (const float4*)Wk, (const float4*)Wv,
      (const float4*)Wo, (ushort4*)xb, (ushort4*)wqkv, (ushort4*)(wqkv + 4194304),
      (ushort4*)(wqkv + 2 * 4194304), (ushort4*)wob);

  // fused QKV: M=4096, N=6144, K=2048
  gemm_qkv<<<dim3(48, 32), 256, 0, stream>>>(xb, wqkv, Qb, Kb, Vtb, 4096, 6144, 2048);

  flash_kernel<<<dim3(16, 32), 256, 0, stream>>>(Qb, Kb, Vtb, Ob, stats);

  // merged tail: 512 proj blocks + 8192 probs blocks
  tail_kernel<<<8704, 256, 0, stream>>>(Ob, wob, outp, bo, Qb, Kb, stats, attnp);
}